// Round 8
// baseline (489.070 us; speedup 1.0000x reference)
//
#include <hip/hip_runtime.h>
#include <hip/hip_bf16.h>
#include <math.h>

// Problem dims
#define B_SZ    2
#define L_SZ    1024
#define DMODEL  2048
#define DINNER  4096
#define DSTATE  16
#define DCONV   4
#define DTRANK  128
#define NROWS   (B_SZ * L_SZ)          // 2048 token rows
#define NCHUNK  16
#define CHUNKLEN (L_SZ / NCHUNK)       // 64

typedef __hip_bfloat16 bf16;
typedef __attribute__((ext_vector_type(8))) short  short8;
typedef __attribute__((ext_vector_type(4))) float  floatx4;

static __device__ __forceinline__ float b2f(bf16 v) { return __bfloat162float(v); }
static __device__ __forceinline__ bf16  f2b(float v) { return __float2bfloat16(v); }
static __device__ __forceinline__ short f2bs(float v) {
    return (short)__builtin_bit_cast(unsigned short, __float2bfloat16(v));
}

static __device__ __forceinline__ void cvt8(const short8 v, float* out) {
    #pragma unroll
    for (int i = 0; i < 8; i++) {
        unsigned int u = ((unsigned int)(unsigned short)v[i]) << 16;
        out[i] = __builtin_bit_cast(float, u);
    }
}

static __device__ __forceinline__ float softplus_safe(float x) {
    return fmaxf(x, 0.f) + log1pf(__expf(-fabsf(x)));
}

static __device__ __forceinline__ void gload_lds16(const bf16* g, bf16* l) {
    __builtin_amdgcn_global_load_lds(
        (const __attribute__((address_space(1))) void*)g,
        (__attribute__((address_space(3))) void*)l,
        16, 0, 0);
}

// NOTE (round-6 post-mortem): XCD-chunked block swizzle REMOVED. Measured A/B:
// default round-robin gives each XCD the same small set of n-panels across all
// m-rows (B-panel L2-resident, FETCH 49 GB); m-chunking forced each XCD to
// stream the whole B matrix (FETCH 135 GB, G1 +5 us). Default mapping wins
// for these M<<N / small-grid shapes.

// ---------------------------------------------------------------------------
__global__ void probe_kernel(const void* nw, int* flag) {
    if (threadIdx.x == 0 && blockIdx.x == 0) {
        const unsigned short* p = (const unsigned short*)nw;
        *flag = (p[0] == 0x3F80u) ? 0 : 1;   // 0 = bf16 inputs (unexpected)
    }
}
__global__ void assert_fp32_kernel(const int* flag, float* out) {
    if (*flag == 0) out[blockIdx.x * 256 + threadIdx.x] = 888.0f;
}
__global__ void fill_diag_kernel(unsigned short* out, int n) {
    int i = blockIdx.x * 256 + threadIdx.x;
    if (i < n) out[i] = 0x4442;
}

// fp32 -> bf16 convert, 8 elems/thread, vectorized 16B store (round-6:
// old version used 4 scalar bf16 stores — Common-mistake #2, store side)
__global__ __launch_bounds__(256) void cvt_w_kernel(
    const float* __restrict__ in, bf16* __restrict__ out, int n)
{
    int i = (blockIdx.x * 256 + threadIdx.x) * 8;
    if (i < n) {
        float4 a = *(const float4*)(in + i);
        float4 b = *(const float4*)(in + i + 4);
        short8 o;
        o[0] = f2bs(a.x); o[1] = f2bs(a.y); o[2] = f2bs(a.z); o[3] = f2bs(a.w);
        o[4] = f2bs(b.x); o[5] = f2bs(b.y); o[6] = f2bs(b.z); o[7] = f2bs(b.w);
        *(short8*)(out + i) = o;
    }
}

// ---------------------------------------------------------------------------
// K0: hs = rmsnorm(hidden + residual) * w (bf16). Residual output deferred.
// ---------------------------------------------------------------------------
__global__ __launch_bounds__(256) void addnorm_kernel(
    const float* __restrict__ h, const float* __restrict__ r,
    const float* __restrict__ w, bf16* __restrict__ hs_out)
{
    const int row = blockIdx.x;
    const int t   = threadIdx.x;
    const size_t base = (size_t)row * DMODEL;

    float vals[8];
    float ss = 0.f;
    #pragma unroll
    for (int i = 0; i < 8; i++) {
        int c = t + i * 256;
        float v = h[base + c] + r[base + c];
        vals[i] = v;
        ss += v * v;
    }
    #pragma unroll
    for (int off = 32; off > 0; off >>= 1) ss += __shfl_down(ss, off);
    __shared__ float wsum[4];
    if ((t & 63) == 0) wsum[t >> 6] = ss;
    __syncthreads();
    float tot = wsum[0] + wsum[1] + wsum[2] + wsum[3];
    float scale = rsqrtf(tot / (float)DMODEL + 1e-5f);

    #pragma unroll
    for (int i = 0; i < 8; i++) {
        int c = t + i * 256;
        hs_out[base + c] = f2b(vals[i] * scale * w[c]);
    }
}

// final: residual output = hidden + residual (fp32), float4 vectorized
__global__ __launch_bounds__(256) void residual_out_kernel(
    const float* __restrict__ h, const float* __restrict__ r,
    float* __restrict__ resp)
{
    int i = (blockIdx.x * 256 + threadIdx.x) * 4;
    float4 a = *(const float4*)(h + i);
    float4 b = *(const float4*)(r + i);
    float4 o = {a.x + b.x, a.y + b.y, a.z + b.z, a.w + b.w};
    *(float4*)(resp + i) = o;
}

// outp += C1 (fp32, float4)
__global__ __launch_bounds__(256) void addf_kernel(
    float* __restrict__ outp, const float* __restrict__ c1)
{
    int i = (blockIdx.x * 256 + threadIdx.x) * 4;
    float4 a = *(const float4*)(outp + i);
    float4 b = *(const float4*)(c1 + i);
    float4 o = {a.x + b.x, a.y + b.y, a.z + b.z, a.w + b.w};
    *(float4*)(outp + i) = o;
}

// ---------------------------------------------------------------------------
// G1: 256x256 tile, BK=32, 8 waves (2M x 4N), ring-4 LDS quad-buffer,
// counted vmcnt (never 0 in steady state), setprio MFMA, swizzle v2
// (conflict-free: SQ_LDS_BANK_CONFLICT = 0 measured). Verified 70.4 us.
// Schedule is the local optimum of this structure (r3 X/Y split: 75.6;
// r4 drain-free: 98.7; r5 XCD-chunk: 75.2 — all regressed). Do not touch.
// C[M,N](bf16) = A[M,K](bf16) * B[N,K]^T(bf16).
// ---------------------------------------------------------------------------
__global__ __launch_bounds__(512, 2) void gemm_bigtile(
    const bf16* __restrict__ A, const bf16* __restrict__ B,
    bf16* __restrict__ C, int N, int K, int lda, int ldb, int ldc)
{
    __shared__ bf16 sA[4][8192];   // 4 x [256 rows][32 cols]  (64 KiB)
    __shared__ bf16 sB[4][8192];   // 4 x [256 rows][32 cols]  (64 KiB)

    const int t     = threadIdx.x;
    const int lane  = t & 63;
    const int w     = t >> 6;        // 0..7
    const int wm    = w & 1;         // M half (128 rows)
    const int wn    = w >> 1;        // 0..3 (64 cols)
    const int idx16 = lane & 15;
    const int quad  = lane >> 4;

    const int tilesN = N >> 8;
    const int bid    = blockIdx.x;               // default mapping (see NOTE)
    const int m_blk  = (bid / tilesN) << 8;
    const int n_blk  = (bid % tilesN) << 8;

    const int srow  = t >> 2;
    const int sslot = t & 3;
    const int gswz  = ((sslot ^ ((srow >> 1) & 3)) << 3);   // bf16 elems
    const bf16* gA = A + (size_t)(m_blk + srow) * lda + gswz;
    const bf16* gB = B + (size_t)(n_blk + srow) * ldb + gswz;

    bf16* ldsA = &sA[0][0] + (w << 9);   // wave-uniform base (+512 elems/wave)
    bf16* ldsB = &sB[0][0] + (w << 9);

    // frag rows are R0+idx16 with R0 multiple of 16 -> f(row) = (idx16>>1)&3
    const int rswz = ((quad ^ ((idx16 >> 1) & 3)) << 3);
    const int aoff = ((wm << 7) + idx16) * 32 + rswz;
    const int boff = ((wn << 6) + idx16) * 32 + rswz;

#define STAGE_A(tt) do { const int _r = (tt) & 3; const size_t _k = (size_t)(tt) << 5; \
    gload_lds16(gA + _k,                      ldsA + _r * 8192); \
    gload_lds16(gA + ((size_t)lda << 7) + _k, ldsA + _r * 8192 + 4096); } while (0)
#define STAGE_B(tt) do { const int _r = (tt) & 3; const size_t _k = (size_t)(tt) << 5; \
    gload_lds16(gB + _k,                      ldsB + _r * 8192); \
    gload_lds16(gB + ((size_t)ldb << 7) + _k, ldsB + _r * 8192 + 4096); } while (0)

    floatx4 acc[8][4] = {};
    const int NT = K >> 5;

    STAGE_A(0); STAGE_B(0);
    STAGE_A(1); STAGE_B(1);
    STAGE_A(2); STAGE_B(2);
    asm volatile("s_waitcnt vmcnt(8)" ::: "memory");
    __builtin_amdgcn_s_barrier();
    __builtin_amdgcn_sched_barrier(0);

    #pragma unroll 1
    for (int tt = 0; tt < NT; ++tt) {
        const bf16* la = &sA[tt & 3][0] + aoff;
        const bf16* lb = &sB[tt & 3][0] + boff;

        short8 af[4], bfr[4];
        #pragma unroll
        for (int i = 0; i < 4; i++) af[i]  = *(const short8*)(la + i * 512);
        #pragma unroll
        for (int j = 0; j < 4; j++) bfr[j] = *(const short8*)(lb + j * 512);
        if (tt + 3 < NT) STAGE_A(tt + 3);
        asm volatile("s_waitcnt lgkmcnt(0)" ::: "memory");
        __builtin_amdgcn_sched_barrier(0);
        __builtin_amdgcn_s_setprio(1);
        #pragma unroll
        for (int i = 0; i < 4; i++)
            #pragma unroll
            for (int j = 0; j < 4; j++)
                acc[i][j] = __builtin_amdgcn_mfma_f32_16x16x32_bf16(
                    af[i], bfr[j], acc[i][j], 0, 0, 0);
        __builtin_amdgcn_s_setprio(0);

        short8 ag[4];
        #pragma unroll
        for (int i = 0; i < 4; i++) ag[i] = *(const short8*)(la + (i + 4) * 512);
        if (tt + 3 < NT) STAGE_B(tt + 3);
        asm volatile("s_waitcnt lgkmcnt(0)" ::: "memory");
        __builtin_amdgcn_sched_barrier(0);
        __builtin_amdgcn_s_setprio(1);
        #pragma unroll
        for (int i = 0; i < 4; i++)
            #pragma unroll
            for (int j = 0; j < 4; j++)
                acc[i + 4][j] = __builtin_amdgcn_mfma_f32_16x16x32_bf16(
                    ag[i], bfr[j], acc[i + 4][j], 0, 0, 0);
        __builtin_amdgcn_s_setprio(0);

        const int ahead = NT - 1 - tt;
        if (ahead >= 3)      asm volatile("s_waitcnt vmcnt(8)" ::: "memory");
        else if (ahead == 2) asm volatile("s_waitcnt vmcnt(4)" ::: "memory");
        else if (ahead == 1) asm volatile("s_waitcnt vmcnt(0)" ::: "memory");
        if (ahead > 0) {
            __builtin_amdgcn_s_barrier();
            __builtin_amdgcn_sched_barrier(0);
        }
    }
#undef STAGE_A
#undef STAGE_B

    #pragma unroll
    for (int i = 0; i < 8; i++) {
        #pragma unroll
        for (int j = 0; j < 4; j++) {
            const int r0 = m_blk + (wm << 7) + i * 16 + quad * 4;
            const int c  = n_blk + (wn << 6) + j * 16 + idx16;
            #pragma unroll
            for (int rr = 0; rr < 4; rr++)
                C[(size_t)(r0 + rr) * ldc + c] = f2b(acc[i][j][rr]);
        }
    }
}

// ---------------------------------------------------------------------------
// G4 split-K=2 variant: grid = 2*256 blocks; ks = bid>>8.
// Swizzle v2 LDS (source-side + read-side); default block mapping (see NOTE).
// ---------------------------------------------------------------------------
__global__ __launch_bounds__(256) void gemm_lds_sk2(
    const bf16* __restrict__ A, const bf16* __restrict__ B,
    float* __restrict__ C0, float* __restrict__ C1)
{
    __shared__ bf16 As[128 * 32];
    __shared__ bf16 Bs[128 * 32];

    const int t    = threadIdx.x;
    const int lane = t & 63;
    const int wave = t >> 6;
    const int ks   = blockIdx.x >> 8;
    const int bid  = blockIdx.x & 255;
    const int m_blk = (bid >> 4) * 128;
    const int n_blk = (bid & 15) * 128;
    const int kbase = ks * 2048;

    const int idx16 = lane & 15;
    const int quad  = lane >> 4;
    const int wm = (wave & 1) * 64;
    const int wn = (wave >> 1) * 64;

    const int row_s = t >> 2;
    const int koff  = ((t & 3) ^ ((row_s >> 1) & 3)) * 8;   // src-side swizzle
    const bf16* gA = A + (size_t)(m_blk + row_s) * 4096 + koff + kbase;
    const bf16* gB = B + (size_t)(n_blk + row_s) * 4096 + koff + kbase;
    bf16* lA = As + wave * 512;
    bf16* lB = Bs + wave * 512;

    const int rswz = (quad ^ ((idx16 >> 1) & 3)) * 8;       // read-side swizzle

    floatx4 acc[4][4] = {};

    for (int k0 = 0; k0 < 2048; k0 += 32) {
        gload_lds16(gA + k0,                    lA);
        gload_lds16(gA + (size_t)64 * 4096 + k0, lA + 2048);
        gload_lds16(gB + k0,                    lB);
        gload_lds16(gB + (size_t)64 * 4096 + k0, lB + 2048);
        __syncthreads();

        short8 af[4], bfr[4];
        #pragma unroll
        for (int i = 0; i < 4; i++)
            af[i]  = *(const short8*)(As + (wm + i * 16 + idx16) * 32 + rswz);
        #pragma unroll
        for (int j = 0; j < 4; j++)
            bfr[j] = *(const short8*)(Bs + (wn + j * 16 + idx16) * 32 + rswz);
        #pragma unroll
        for (int i = 0; i < 4; i++)
            #pragma unroll
            for (int j = 0; j < 4; j++)
                acc[i][j] = __builtin_amdgcn_mfma_f32_16x16x32_bf16(
                    af[i], bfr[j], acc[i][j], 0, 0, 0);
        __syncthreads();
    }

    float* C = ks ? C1 : C0;
    #pragma unroll
    for (int i = 0; i < 4; i++) {
        #pragma unroll
        for (int j = 0; j < 4; j++) {
            const int r0 = m_blk + wm + i * 16 + quad * 4;
            const int c  = n_blk + wn + j * 16 + idx16;
            #pragma unroll
            for (int r = 0; r < 4; r++)
                C[(size_t)(r0 + r) * DMODEL + c] = acc[i][j][r];
        }
    }
}

// ---------------------------------------------------------------------------
// G2 split-K=4 (unchanged)
// ---------------------------------------------------------------------------
__global__ __launch_bounds__(256) void gemm_g2_sk(
    const bf16* __restrict__ x, const bf16* __restrict__ W,
    float* __restrict__ part)
{
    const int lane = threadIdx.x & 63;
    const int gw   = blockIdx.x * 4 + (threadIdx.x >> 6);  // 0..5119
    const int tile = gw >> 2;
    const int s    = gw & 3;
    const int wm = tile / 10;       // 0..127
    const int wn = tile % 10;       // 0..9
    const int idx16 = lane & 15, quad = lane >> 4;
    const int k0 = s * 1024;

    floatx4 acc = {};
    const bf16* Ap = x + (size_t)(wm * 16 + idx16) * DINNER + quad * 8 + k0;
    const bf16* Bp = W + (size_t)(wn * 16 + idx16) * DINNER + quad * 8 + k0;
    for (int k = 0; k < 1024; k += 32) {
        short8 af  = *(const short8*)(Ap + k);
        short8 bfr = *(const short8*)(Bp + k);
        acc = __builtin_amdgcn_mfma_f32_16x16x32_bf16(af, bfr, acc, 0, 0, 0);
    }
    #pragma unroll
    for (int r = 0; r < 4; r++)
        part[((size_t)s * NROWS + wm * 16 + quad * 4 + r) * 160 + wn * 16 + idx16]
            = acc[r];
}

__global__ __launch_bounds__(256) void g2_reduce_kernel(
    const float* __restrict__ part, bf16* __restrict__ xdbl)
{
    int i = blockIdx.x * 256 + threadIdx.x;        // over 2048*160
    float v = part[i] + part[327680 + i] + part[2 * 327680 + i]
            + part[3 * 327680 + i];
    xdbl[i] = f2b(v);
}

// ---------------------------------------------------------------------------
// G3 direct (unchanged)
// ---------------------------------------------------------------------------
__global__ __launch_bounds__(256) void gemm_g3_direct(
    const bf16* __restrict__ xdbl, const bf16* __restrict__ W,
    const float* __restrict__ bias, bf16* __restrict__ dtout)
{
    const int lane = threadIdx.x & 63;
    const int gw   = blockIdx.x * 4 + (threadIdx.x >> 6);  // 0..32767
    const int wm = gw >> 8;         // 0..127
    const int wn = gw & 255;        // 0..255
    const int idx16 = lane & 15, quad = lane >> 4;

    floatx4 acc = {};
    const bf16* Ap = xdbl + (size_t)(wm * 16 + idx16) * 160 + quad * 8;
    const bf16* Bp = W + (size_t)(wn * 16 + idx16) * DTRANK + quad * 8;
    #pragma unroll
    for (int k = 0; k < 128; k += 32) {
        short8 af  = *(const short8*)(Ap + k);
        short8 bfr = *(const short8*)(Bp + k);
        acc = __builtin_amdgcn_mfma_f32_16x16x32_bf16(af, bfr, acc, 0, 0, 0);
    }
    const int c = wn * 16 + idx16;
    const float bv = bias[c];
    #pragma unroll
    for (int r = 0; r < 4; r++)
        dtout[(size_t)(wm * 16 + quad * 4 + r) * (2 * DINNER) + c]
            = f2b(softplus_safe(acc[r] + bv));
}

// ---------------------------------------------------------------------------
// K2: depthwise causal conv + bias + silu, 8 d-elems/thread (short8/float4)
// ---------------------------------------------------------------------------
__global__ __launch_bounds__(256) void conv_silu_kernel(
    const bf16* __restrict__ xz, const float* __restrict__ cw,
    const float* __restrict__ cb, bf16* __restrict__ xout)
{
    const int idx = (blockIdx.x * 256 + threadIdx.x) * 8;   // over NROWS*DINNER
    const int d0 = idx & (DINNER - 1);                      // multiple of 8
    const int bl = idx >> 12;
    const int l  = bl & (L_SZ - 1);
    const int b  = bl >> 10;

    float acc[8];
    {
        float4 c0 = *(const float4*)(cb + d0);
        float4 c1 = *(const float4*)(cb + d0 + 4);
        acc[0] = c0.x; acc[1] = c0.y; acc[2] = c0.z; acc[3] = c0.w;
        acc[4] = c1.x; acc[5] = c1.y; acc[6] = c1.z; acc[7] = c1.w;
    }
    floatx4 cwv[8];
    #pragma unroll
    for (int i = 0; i < 8; i++)
        cwv[i] = *(const floatx4*)(cw + (size_t)(d0 + i) * DCONV);

    #pragma unroll
    for (int t = 0; t < DCONV; t++) {
        int ls = l - (DCONV - 1) + t;
        if (ls >= 0) {
            short8 v = *(const short8*)(xz + ((size_t)(b * L_SZ + ls)) * (2 * DINNER) + d0);
            float xf[8]; cvt8(v, xf);
            #pragma unroll
            for (int i = 0; i < 8; i++) acc[i] += cwv[i][t] * xf[i];
        }
    }
    short8 o;
    #pragma unroll
    for (int i = 0; i < 8; i++) {
        float s = acc[i] / (1.f + __expf(-acc[i]));
        o[i] = f2bs(s);
    }
    *(short8*)(xout + idx) = o;
}

// ---------------------------------------------------------------------------
// Chunked selective scan — pair-split states (8/thread), LDS-staged f32 B/C,
// time-loop unrolled x4 with grouped loads.  (verified round 2)
// ---------------------------------------------------------------------------
__global__ __launch_bounds__(256) void scan_part1(
    const bf16* __restrict__ xz, const bf16* __restrict__ x,
    const bf16* __restrict__ xdbl, const float* __restrict__ A_log,
    float* __restrict__ hpart, float* __restrict__ dtsum)
{
    __shared__ float sBC[64 * 32];          // 8KB: chunk rows, cols B(16)|C(16)
    const int tid = threadIdx.x, bid = blockIdx.x;
    const int sub = tid & 1;
    const int d   = ((bid & 31) << 7) + (tid >> 1);
    const int b   = (bid >> 5) & 1;
    const int c   = bid >> 6;
    const size_t row0 = (size_t)b * L_SZ + c * CHUNKLEN;

    {   // stage B/C -> f32 LDS (2048 elems, 8/thread)
        int r = tid >> 2, sl = tid & 3;
        short8 v = *(const short8*)(xdbl + (row0 + r) * 160 + DTRANK + sl * 8);
        float tmp[8]; cvt8(v, tmp);
        #pragma unroll
        for (int i = 0; i < 8; i++) sBC[r * 32 + sl * 8 + i] = tmp[i];
    }
    __syncthreads();

    float Aa[8];
    #pragma unroll
    for (int s = 0; s < 8; s++)
        Aa[s] = -__expf(A_log[d * DSTATE + sub * 8 + s]);

    float h[8] = {};
    float dts = 0.f;
    const floatx4* BC4 = (const floatx4*)sBC;
    const int bc0 = sub * 2;

    #pragma unroll 1
    for (int l0 = 0; l0 < CHUNKLEN; l0 += 4) {
        float dtv[4], xv[4];
        #pragma unroll
        for (int u = 0; u < 4; u++) {
            const size_t rbl = row0 + l0 + u;
            dtv[u] = b2f(xz[rbl * (2 * DINNER) + d]);
            xv[u]  = b2f(x[rbl * DINNER + d]);
        }
        #pragma unroll
        for (int u = 0; u < 4; u++) {
            const int l = l0 + u;
            floatx4 B0 = BC4[l * 8 + bc0];
            floatx4 B1 = BC4[l * 8 + bc0 + 1];
            dts += dtv[u];
            float dx = dtv[u] * xv[u];
            #pragma unroll
            for (int s = 0; s < 4; s++)
                h[s] = __expf(dtv[u] * Aa[s]) * h[s] + dx * B0[s];
            #pragma unroll
            for (int s = 0; s < 4; s++)
                h[s + 4] = __expf(dtv[u] * Aa[s + 4]) * h[s + 4] + dx * B1[s];
        }
    }
    const size_t sbase = ((size_t)((b * DINNER + d) * NCHUNK + c)) * 16 + sub * 8;
    *(floatx4*)(hpart + sbase)     = (floatx4){h[0], h[1], h[2], h[3]};
    *(floatx4*)(hpart + sbase + 4) = (floatx4){h[4], h[5], h[6], h[7]};
    if (!sub) dtsum[(b * DINNER + d) * NCHUNK + c] = dts;
}

__global__ __launch_bounds__(256) void scan_part2(
    const float* __restrict__ A_log, float* hpart,
    const float* __restrict__ dtsum)
{
    const int t = blockIdx.x * 256 + threadIdx.x;
    const int s = t & 15;
    const int d = (t >> 4) & (DINNER - 1);
    const int b = t >> 16;
    const float Aa = -__expf(A_log[d * DSTATE + s]);
    const size_t base = (size_t)(b * DINNER + d) * NCHUNK;
    float h = 0.f;
    #pragma unroll
    for (int c = 0; c < NCHUNK; c++) {
        float tmp = hpart[(base + c) * 16 + s];
        hpart[(base + c) * 16 + s] = h;
        h = __expf(Aa * dtsum[base + c]) * h + tmp;
    }
}

__global__ __launch_bounds__(256) void scan_part3(
    const bf16* __restrict__ xz, const bf16* x,
    const bf16* __restrict__ xdbl, const float* __restrict__ A_log,
    const float* __restrict__ Dp, const float* __restrict__ hpart,
    bf16* y)
{
    __shared__ float sBC[64 * 32];
    const int tid = threadIdx.x, bid = blockIdx.x;
    const int sub = tid & 1;
    const int d   = ((bid & 31) << 7) + (tid >> 1);
    const int b   = (bid >> 5) & 1;
    const int c   = bid >> 6;
    const size_t row0 = (size_t)b * L_SZ + c * CHUNKLEN;

    {   // stage B/C -> f32 LDS
        int r = tid >> 2, sl = tid & 3;
        short8 v = *(const short8*)(xdbl + (row0 + r) * 160 + DTRANK + sl * 8);
        float tmp[8]; cvt8(v, tmp);
        #pragma unroll
        for (int i = 0; i < 8; i++) sBC[r * 32 + sl * 8 + i] = tmp[i];
    }
    __syncthreads();

    float Aa[8];
    #pragma unroll
    for (int s = 0; s < 8; s++)
        Aa[s] = -__expf(A_log[d * DSTATE + sub * 8 + s]);
    const float Dv = Dp[d];

    float h[8];
    const size_t sbase = ((size_t)((b * DINNER + d) * NCHUNK + c)) * 16 + sub * 8;
    {
        floatx4 h0 = *(const floatx4*)(hpart + sbase);
        floatx4 h1 = *(const floatx4*)(hpart + sbase + 4);
        #pragma unroll
        for (int s = 0; s < 4; s++) { h[s] = h0[s]; h[s + 4] = h1[s]; }
    }

    const floatx4* BC4 = (const floatx4*)sBC;
    const int bc0 = sub * 2;

    #pragma unroll 1
    for (int l0 = 0; l0 < CHUNKLEN; l0 += 4) {
        float dtv[4], xv[4], zv[4];
        #pragma unroll
        for (int u = 0; u < 4; u++) {
            const size_t rbl = row0 + l0 + u;
            dtv[u] = b2f(xz[rbl * (2 * DINNER) + d]);
            xv[u]  = b2f(x[rbl * DINNER + d]);
            zv[u]  = b2f(xz[rbl * (2 * DINNER) + DINNER + d]);
        }
        #pragma unroll
        for (int u = 0; u < 4; u++) {
            const int l = l0 + u;
            floatx4 B0 = BC4[l * 8 + bc0];
            floatx4 B1 = BC4[l * 8 + bc0 + 1];
            floatx4 C0 = BC4[l * 8 + 4 + bc0];
            floatx4 C1 = BC4[l * 8 + 4 + bc0 + 1];
            float dx = dtv[u] * xv[u];
            float ys = 0.f;
            #pragma unroll
            for (int s = 0; s < 4; s++) {
                h[s] = __expf(dtv[u] * Aa[s]) * h[s] + dx * B0[s];
                ys += h[s] * C0[s];
            }
            #pragma unroll
            for (int s = 0; s < 4; s++) {
                h[s + 4] = __expf(dtv[u] * Aa[s + 4]) * h[s + 4] + dx * B1[s];
                ys += h[s + 4] * C1[s];
            }
            ys += __shfl_xor(ys, 1);
            if (!sub) {
                const size_t rbl = row0 + l;
                float sig = zv[u] / (1.f + __expf(-zv[u]));
                y[rbl * DINNER + d] = f2b((ys + xv[u] * Dv) * sig);
            }
        }
    }
}

// ---------------------------------------------------------------------------
extern "C" void kernel_launch(void* const* d_in, const int* in_sizes, int n_in,
                              void* d_out, int out_size, void* d_ws, size_t ws_size,
                              hipStream_t stream)
{
    // ws (proven >= 50,987,012 B):
    //   [0, 32MB)        xz bf16 [2048][8192]; dead after scan_p3 -> G4's C1 (fp32 16.8MB)
    //   [32MB, 48MB)     hs bf16 (8.4MB, dead after G1) -> x bf16 [2048][4096] -> y alias
    //   [48MB, +640KB)   xdbl bf16 [2048][160]
    //   +4B              dtype flag
    // d_out (33.5MB) phase-by-phase: see round-0 comment (unchanged).
    const size_t WS_NEED = 33554432ull + 16777216ull + 655360ull + 4ull;
    if (ws_size < WS_NEED) {
        fill_diag_kernel<<<(out_size + 255) / 256, 256, 0, stream>>>(
            (unsigned short*)d_out, out_size);
        return;
    }

    char* ws = (char*)d_ws;
    bf16*  xz    = (bf16*)(ws);
    float* c1    = (float*)(ws);                 // G4 partial (xz dead)
    bf16*  hs    = (bf16*)(ws + 33554432);
    bf16*  x     = (bf16*)(ws + 33554432);       // overwrites dead hs
    bf16*  y     = x;
    bf16*  xdbl  = (bf16*)(ws + 50331648);
    int*   flag  = (int*)(ws + 50987008);

    char* od = (char*)d_out;
    bf16*  w1bf  = (bf16*)od;                     // phase A
    bf16*  wdtbf = (bf16*)od;                     // phase B
    bf16*  wxbf  = (bf16*)(od + 1048576);
    float* dtsum = (float*)(od + 2359296);
    float* hpart = (float*)(od + 2883584);
    float* g2part= (float*)(od + 11272192);       // 5.24MB, ends 16.52MB
    bf16*  wobf  = (bf16*)(od + 16777216);
    float* outp  = (float*)d_out;
    float* resp  = (float*)d_out + (size_t)NROWS * DMODEL;

    const float* hid = (const float*)d_in[0];
    const float* res = (const float*)d_in[1];
    const float* nw  = (const float*)d_in[2];
    const float* w1  = (const float*)d_in[3];
    const float* cw  = (const float*)d_in[4];
    const float* cb  = (const float*)d_in[5];
    const float* wx  = (const float*)d_in[6];
    const float* wdt = (const float*)d_in[7];
    const float* bdt = (const float*)d_in[8];
    const float* Al  = (const float*)d_in[9];
    const float* Dp  = (const float*)d_in[10];
    const float* wo  = (const float*)d_in[11];

    probe_kernel<<<1, 64, 0, stream>>>(d_in[2], flag);

    // Phase A: hs + full w1bf, then single-launch G1 (256 blocks = 1 blk/CU)
    addnorm_kernel<<<NROWS, 256, 0, stream>>>(hid, res, nw, hs);
    cvt_w_kernel<<<(2 * DINNER * DMODEL) / 2048, 256, 0, stream>>>(
        w1, w1bf, 2 * DINNER * DMODEL);
    gemm_bigtile<<<(2048 / 256) * (8192 / 256), 512, 0, stream>>>(
        hs, w1bf, xz, 2 * DINNER, DMODEL, DMODEL, DMODEL, 2 * DINNER);

    // Phase B: d_out is dead scratch
    cvt_w_kernel<<<(DINNER * DTRANK) / 2048, 256, 0, stream>>>(
        wdt, wdtbf, DINNER * DTRANK);
    cvt_w_kernel<<<(160 * DINNER) / 2048, 256, 0, stream>>>(
        wx, wxbf, 160 * DINNER);
    cvt_w_kernel<<<(DMODEL * DINNER) / 2048, 256, 0, stream>>>(
        wo, wobf, DMODEL * DINNER);

    conv_silu_kernel<<<(NROWS * DINNER) / 2048, 256, 0, stream>>>(xz, cw, cb, x);

    // G2: split-K=4 direct MFMA -> fp32 partials -> bf16 xdbl
    gemm_g2_sk<<<1280, 256, 0, stream>>>(x, wxbf, g2part);
    g2_reduce_kernel<<<(NROWS * 160) / 256, 256, 0, stream>>>(g2part, xdbl);

    // G3: direct K=128 GEMM + softplus -> dt into xz x-half
    gemm_g3_direct<<<8192, 256, 0, stream>>>(xdbl, wdtbf, bdt, xz);

    // chunked scan (pair-split: 2 threads per (b,d,c))
    scan_part1<<<(NCHUNK * B_SZ * DINNER * 2) / 256, 256, 0, stream>>>(
        xz, x, xdbl, Al, hpart, dtsum);
    scan_part2<<<(B_SZ * DINNER * DSTATE) / 256, 256, 0, stream>>>(
        Al, hpart, dtsum);
    scan_part3<<<(NCHUNK * B_SZ * DINNER * 2) / 256, 256, 0, stream>>>(
        xz, x, xdbl, Al, Dp, hpart, y);

    // Phase C: G4 split-K=2 (C0 = outp, C1 = dead xz region), then sum
    gemm_lds_sk2<<<512, 256, 0, stream>>>(y, wobf, outp, c1);
    addf_kernel<<<(NROWS * DMODEL) / 1024, 256, 0, stream>>>(outp, c1);

    // Phase D: residual output (wobf region now dead)
    residual_out_kernel<<<(NROWS * DMODEL) / 1024, 256, 0, stream>>>(
        hid, res, resp);

    assert_fp32_kernel<<<16, 256, 0, stream>>>(flag, outp);
}

// Round 9
// 477.745 us; speedup vs baseline: 1.0237x; 1.0237x over previous
//
#include <hip/hip_runtime.h>
#include <hip/hip_bf16.h>
#include <math.h>

// Problem dims
#define B_SZ    2
#define L_SZ    1024
#define DMODEL  2048
#define DINNER  4096
#define DSTATE  16
#define DCONV   4
#define DTRANK  128
#define NROWS   (B_SZ * L_SZ)          // 2048 token rows
#define NCHUNK  16
#define CHUNKLEN (L_SZ / NCHUNK)       // 64

typedef __hip_bfloat16 bf16;
typedef __attribute__((ext_vector_type(8))) short  short8;
typedef __attribute__((ext_vector_type(4))) float  floatx4;

static __device__ __forceinline__ float b2f(bf16 v) { return __bfloat162float(v); }
static __device__ __forceinline__ bf16  f2b(float v) { return __float2bfloat16(v); }
static __device__ __forceinline__ short f2bs(float v) {
    return (short)__builtin_bit_cast(unsigned short, __float2bfloat16(v));
}

static __device__ __forceinline__ void cvt8(const short8 v, float* out) {
    #pragma unroll
    for (int i = 0; i < 8; i++) {
        unsigned int u = ((unsigned int)(unsigned short)v[i]) << 16;
        out[i] = __builtin_bit_cast(float, u);
    }
}

static __device__ __forceinline__ float softplus_safe(float x) {
    return fmaxf(x, 0.f) + log1pf(__expf(-fabsf(x)));
}

static __device__ __forceinline__ void gload_lds16(const bf16* g, bf16* l) {
    __builtin_amdgcn_global_load_lds(
        (const __attribute__((address_space(1))) void*)g,
        (__attribute__((address_space(3))) void*)l,
        16, 0, 0);
}

// NOTE (round-6 post-mortem): XCD-chunked block swizzle REMOVED. Measured A/B:
// default round-robin gives each XCD the same small set of n-panels across all
// m-rows (B-panel L2-resident, FETCH 49 GB); m-chunking forced each XCD to
// stream the whole B matrix (FETCH 135 GB, G1 +5 us). Default mapping wins
// for these M<<N / small-grid shapes.

// ---------------------------------------------------------------------------
__global__ void probe_kernel(const void* nw, int* flag) {
    if (threadIdx.x == 0 && blockIdx.x == 0) {
        const unsigned short* p = (const unsigned short*)nw;
        *flag = (p[0] == 0x3F80u) ? 0 : 1;   // 0 = bf16 inputs (unexpected)
    }
}
__global__ void assert_fp32_kernel(const int* flag, float* out) {
    if (*flag == 0) out[blockIdx.x * 256 + threadIdx.x] = 888.0f;
}
__global__ void fill_diag_kernel(unsigned short* out, int n) {
    int i = blockIdx.x * 256 + threadIdx.x;
    if (i < n) out[i] = 0x4442;
}

// fp32 -> bf16 convert, 8 elems/thread, vectorized 16B store
__global__ __launch_bounds__(256) void cvt_w_kernel(
    const float* __restrict__ in, bf16* __restrict__ out, int n)
{
    int i = (blockIdx.x * 256 + threadIdx.x) * 8;
    if (i < n) {
        float4 a = *(const float4*)(in + i);
        float4 b = *(const float4*)(in + i + 4);
        short8 o;
        o[0] = f2bs(a.x); o[1] = f2bs(a.y); o[2] = f2bs(a.z); o[3] = f2bs(a.w);
        o[4] = f2bs(b.x); o[5] = f2bs(b.y); o[6] = f2bs(b.z); o[7] = f2bs(b.w);
        *(short8*)(out + i) = o;
    }
}

// ---------------------------------------------------------------------------
// K0: hs = rmsnorm(hidden + residual) * w (bf16). Residual output deferred.
// ---------------------------------------------------------------------------
__global__ __launch_bounds__(256) void addnorm_kernel(
    const float* __restrict__ h, const float* __restrict__ r,
    const float* __restrict__ w, bf16* __restrict__ hs_out)
{
    const int row = blockIdx.x;
    const int t   = threadIdx.x;
    const size_t base = (size_t)row * DMODEL;

    float vals[8];
    float ss = 0.f;
    #pragma unroll
    for (int i = 0; i < 8; i++) {
        int c = t + i * 256;
        float v = h[base + c] + r[base + c];
        vals[i] = v;
        ss += v * v;
    }
    #pragma unroll
    for (int off = 32; off > 0; off >>= 1) ss += __shfl_down(ss, off);
    __shared__ float wsum[4];
    if ((t & 63) == 0) wsum[t >> 6] = ss;
    __syncthreads();
    float tot = wsum[0] + wsum[1] + wsum[2] + wsum[3];
    float scale = rsqrtf(tot / (float)DMODEL + 1e-5f);

    #pragma unroll
    for (int i = 0; i < 8; i++) {
        int c = t + i * 256;
        hs_out[base + c] = f2b(vals[i] * scale * w[c]);
    }
}

// final: residual output = hidden + residual (fp32), float4 vectorized
__global__ __launch_bounds__(256) void residual_out_kernel(
    const float* __restrict__ h, const float* __restrict__ r,
    float* __restrict__ resp)
{
    int i = (blockIdx.x * 256 + threadIdx.x) * 4;
    float4 a = *(const float4*)(h + i);
    float4 b = *(const float4*)(r + i);
    float4 o = {a.x + b.x, a.y + b.y, a.z + b.z, a.w + b.w};
    *(float4*)(resp + i) = o;
}

// outp += C1 (fp32, float4)
__global__ __launch_bounds__(256) void addf_kernel(
    float* __restrict__ outp, const float* __restrict__ c1)
{
    int i = (blockIdx.x * 256 + threadIdx.x) * 4;
    float4 a = *(const float4*)(outp + i);
    float4 b = *(const float4*)(c1 + i);
    float4 o = {a.x + b.x, a.y + b.y, a.z + b.z, a.w + b.w};
    *(float4*)(outp + i) = o;
}

// ---------------------------------------------------------------------------
// G1: 256x256 tile, BK=32, 8 waves (2M x 4N), ring-4 LDS quad-buffer,
// counted vmcnt (never 0 in steady state), setprio MFMA, swizzle v2
// (conflict-free: SQ_LDS_BANK_CONFLICT = 0 measured). Verified 70.4-71.5 us.
// Schedule is the local optimum of this structure (r3 X/Y split: 75.6;
// r4 drain-free: 98.7; r5 XCD-chunk: 75.2 — all regressed). Do not touch.
// C[M,N](bf16) = A[M,K](bf16) * B[N,K]^T(bf16).
// ---------------------------------------------------------------------------
__global__ __launch_bounds__(512, 2) void gemm_bigtile(
    const bf16* __restrict__ A, const bf16* __restrict__ B,
    bf16* __restrict__ C, int N, int K, int lda, int ldb, int ldc)
{
    __shared__ bf16 sA[4][8192];   // 4 x [256 rows][32 cols]  (64 KiB)
    __shared__ bf16 sB[4][8192];   // 4 x [256 rows][32 cols]  (64 KiB)

    const int t     = threadIdx.x;
    const int lane  = t & 63;
    const int w     = t >> 6;        // 0..7
    const int wm    = w & 1;         // M half (128 rows)
    const int wn    = w >> 1;        // 0..3 (64 cols)
    const int idx16 = lane & 15;
    const int quad  = lane >> 4;

    const int tilesN = N >> 8;
    const int bid    = blockIdx.x;               // default mapping (see NOTE)
    const int m_blk  = (bid / tilesN) << 8;
    const int n_blk  = (bid % tilesN) << 8;

    const int srow  = t >> 2;
    const int sslot = t & 3;
    const int gswz  = ((sslot ^ ((srow >> 1) & 3)) << 3);   // bf16 elems
    const bf16* gA = A + (size_t)(m_blk + srow) * lda + gswz;
    const bf16* gB = B + (size_t)(n_blk + srow) * ldb + gswz;

    bf16* ldsA = &sA[0][0] + (w << 9);   // wave-uniform base (+512 elems/wave)
    bf16* ldsB = &sB[0][0] + (w << 9);

    // frag rows are R0+idx16 with R0 multiple of 16 -> f(row) = (idx16>>1)&3
    const int rswz = ((quad ^ ((idx16 >> 1) & 3)) << 3);
    const int aoff = ((wm << 7) + idx16) * 32 + rswz;
    const int boff = ((wn << 6) + idx16) * 32 + rswz;

#define STAGE_A(tt) do { const int _r = (tt) & 3; const size_t _k = (size_t)(tt) << 5; \
    gload_lds16(gA + _k,                      ldsA + _r * 8192); \
    gload_lds16(gA + ((size_t)lda << 7) + _k, ldsA + _r * 8192 + 4096); } while (0)
#define STAGE_B(tt) do { const int _r = (tt) & 3; const size_t _k = (size_t)(tt) << 5; \
    gload_lds16(gB + _k,                      ldsB + _r * 8192); \
    gload_lds16(gB + ((size_t)ldb << 7) + _k, ldsB + _r * 8192 + 4096); } while (0)

    floatx4 acc[8][4] = {};
    const int NT = K >> 5;

    STAGE_A(0); STAGE_B(0);
    STAGE_A(1); STAGE_B(1);
    STAGE_A(2); STAGE_B(2);
    asm volatile("s_waitcnt vmcnt(8)" ::: "memory");
    __builtin_amdgcn_s_barrier();
    __builtin_amdgcn_sched_barrier(0);

    #pragma unroll 1
    for (int tt = 0; tt < NT; ++tt) {
        const bf16* la = &sA[tt & 3][0] + aoff;
        const bf16* lb = &sB[tt & 3][0] + boff;

        short8 af[4], bfr[4];
        #pragma unroll
        for (int i = 0; i < 4; i++) af[i]  = *(const short8*)(la + i * 512);
        #pragma unroll
        for (int j = 0; j < 4; j++) bfr[j] = *(const short8*)(lb + j * 512);
        if (tt + 3 < NT) STAGE_A(tt + 3);
        asm volatile("s_waitcnt lgkmcnt(0)" ::: "memory");
        __builtin_amdgcn_sched_barrier(0);
        __builtin_amdgcn_s_setprio(1);
        #pragma unroll
        for (int i = 0; i < 4; i++)
            #pragma unroll
            for (int j = 0; j < 4; j++)
                acc[i][j] = __builtin_amdgcn_mfma_f32_16x16x32_bf16(
                    af[i], bfr[j], acc[i][j], 0, 0, 0);
        __builtin_amdgcn_s_setprio(0);

        short8 ag[4];
        #pragma unroll
        for (int i = 0; i < 4; i++) ag[i] = *(const short8*)(la + (i + 4) * 512);
        if (tt + 3 < NT) STAGE_B(tt + 3);
        asm volatile("s_waitcnt lgkmcnt(0)" ::: "memory");
        __builtin_amdgcn_sched_barrier(0);
        __builtin_amdgcn_s_setprio(1);
        #pragma unroll
        for (int i = 0; i < 4; i++)
            #pragma unroll
            for (int j = 0; j < 4; j++)
                acc[i + 4][j] = __builtin_amdgcn_mfma_f32_16x16x32_bf16(
                    ag[i], bfr[j], acc[i + 4][j], 0, 0, 0);
        __builtin_amdgcn_s_setprio(0);

        const int ahead = NT - 1 - tt;
        if (ahead >= 3)      asm volatile("s_waitcnt vmcnt(8)" ::: "memory");
        else if (ahead == 2) asm volatile("s_waitcnt vmcnt(4)" ::: "memory");
        else if (ahead == 1) asm volatile("s_waitcnt vmcnt(0)" ::: "memory");
        if (ahead > 0) {
            __builtin_amdgcn_s_barrier();
            __builtin_amdgcn_sched_barrier(0);
        }
    }
#undef STAGE_A
#undef STAGE_B

    #pragma unroll
    for (int i = 0; i < 8; i++) {
        #pragma unroll
        for (int j = 0; j < 4; j++) {
            const int r0 = m_blk + (wm << 7) + i * 16 + quad * 4;
            const int c  = n_blk + (wn << 6) + j * 16 + idx16;
            #pragma unroll
            for (int rr = 0; rr < 4; rr++)
                C[(size_t)(r0 + rr) * ldc + c] = f2b(acc[i][j][rr]);
        }
    }
}

// ---------------------------------------------------------------------------
// G4 (round-8): split-K=2, 128x128 tile, 4 waves (2x2 of 64x64), PORTED to
// the verified ring-4 counted-vmcnt schedule. Counts identical to
// gemm_bigtile's verified ledger: 4 gload_lds/thread/K-tile (2 per matrix),
// prologue 3 tiles = 12 loads, end-of-tile vmcnt(8/4/0) (8 leaves tiles
// t+2,t+3 => tile t+1's 4 oldest complete), stage(t+3)->buf (t-1)&3 retired
// at previous barrier, lgkmcnt(0) before barrier = WAR guard.
// LDS 64 KiB -> 2 blocks/CU; 512 blocks = 8 waves/CU (same TLP as G1).
// Replaces the old 2-barrier single-buffer structure (~590-650 TF class).
// C (fp32) = C0 for ks=0, C1 for ks=1.  M=N=2048, K-half=2048, lda=ldb=4096.
// ---------------------------------------------------------------------------
__global__ __launch_bounds__(256, 2) void gemm_sk2_r4(
    const bf16* __restrict__ A, const bf16* __restrict__ B,
    float* __restrict__ C0, float* __restrict__ C1)
{
    __shared__ bf16 sA[4][4096];   // 4 x [128 rows][32 cols] (32 KiB)
    __shared__ bf16 sB[4][4096];

    const int t    = threadIdx.x;
    const int lane = t & 63;
    const int w    = t >> 6;        // 0..3
    const int wm   = w & 1;         // 64-row half
    const int wn   = w >> 1;        // 64-col half
    const int idx16 = lane & 15;
    const int quad  = lane >> 4;

    const int ks   = blockIdx.x >> 8;
    const int bid  = blockIdx.x & 255;
    const int m_blk = (bid >> 4) * 128;
    const int n_blk = (bid & 15) * 128;
    const int kbase = ks * 2048;

    const int srow  = t >> 2;           // 0..63
    const int sslot = t & 3;
    const int gswz  = ((sslot ^ ((srow >> 1) & 3)) << 3);
    const bf16* gA = A + (size_t)(m_blk + srow) * 4096 + kbase + gswz;
    const bf16* gB = B + (size_t)(n_blk + srow) * 4096 + kbase + gswz;

    bf16* ldsA = &sA[0][0] + (w << 9);  // wave-uniform base (512 elems/wave)
    bf16* ldsB = &sB[0][0] + (w << 9);

    const int rswz = ((quad ^ ((idx16 >> 1) & 3)) << 3);
    const int aoff = ((wm << 6) + idx16) * 32 + rswz;
    const int boff = ((wn << 6) + idx16) * 32 + rswz;

#define STAGE_A(tt) do { const int _r = (tt) & 3; const size_t _k = (size_t)(tt) << 5; \
    gload_lds16(gA + _k,                        ldsA + _r * 4096); \
    gload_lds16(gA + (size_t)64 * 4096 + _k,    ldsA + _r * 4096 + 2048); } while (0)
#define STAGE_B(tt) do { const int _r = (tt) & 3; const size_t _k = (size_t)(tt) << 5; \
    gload_lds16(gB + _k,                        ldsB + _r * 4096); \
    gload_lds16(gB + (size_t)64 * 4096 + _k,    ldsB + _r * 4096 + 2048); } while (0)

    floatx4 acc[4][4] = {};
    const int NT = 2048 >> 5;           // 64

    STAGE_A(0); STAGE_B(0);
    STAGE_A(1); STAGE_B(1);
    STAGE_A(2); STAGE_B(2);
    asm volatile("s_waitcnt vmcnt(8)" ::: "memory");
    __builtin_amdgcn_s_barrier();
    __builtin_amdgcn_sched_barrier(0);

    #pragma unroll 1
    for (int tt = 0; tt < NT; ++tt) {
        const bf16* la = &sA[tt & 3][0] + aoff;
        const bf16* lb = &sB[tt & 3][0] + boff;

        short8 af[4], bfr[4];
        #pragma unroll
        for (int i = 0; i < 4; i++) af[i]  = *(const short8*)(la + i * 512);
        #pragma unroll
        for (int j = 0; j < 4; j++) bfr[j] = *(const short8*)(lb + j * 512);
        if (tt + 3 < NT) { STAGE_A(tt + 3); STAGE_B(tt + 3); }
        asm volatile("s_waitcnt lgkmcnt(0)" ::: "memory");
        __builtin_amdgcn_sched_barrier(0);
        __builtin_amdgcn_s_setprio(1);
        #pragma unroll
        for (int i = 0; i < 4; i++)
            #pragma unroll
            for (int j = 0; j < 4; j++)
                acc[i][j] = __builtin_amdgcn_mfma_f32_16x16x32_bf16(
                    af[i], bfr[j], acc[i][j], 0, 0, 0);
        __builtin_amdgcn_s_setprio(0);

        const int ahead = NT - 1 - tt;
        if (ahead >= 3)      asm volatile("s_waitcnt vmcnt(8)" ::: "memory");
        else if (ahead == 2) asm volatile("s_waitcnt vmcnt(4)" ::: "memory");
        else if (ahead == 1) asm volatile("s_waitcnt vmcnt(0)" ::: "memory");
        if (ahead > 0) {
            __builtin_amdgcn_s_barrier();
            __builtin_amdgcn_sched_barrier(0);
        }
    }
#undef STAGE_A
#undef STAGE_B

    float* C = ks ? C1 : C0;
    #pragma unroll
    for (int i = 0; i < 4; i++) {
        #pragma unroll
        for (int j = 0; j < 4; j++) {
            const int r0 = m_blk + (wm << 6) + i * 16 + quad * 4;
            const int c  = n_blk + (wn << 6) + j * 16 + idx16;
            #pragma unroll
            for (int r = 0; r < 4; r++)
                C[(size_t)(r0 + r) * DMODEL + c] = acc[i][j][r];
        }
    }
}

// ---------------------------------------------------------------------------
// G2 split-K=4 (unchanged)
// ---------------------------------------------------------------------------
__global__ __launch_bounds__(256) void gemm_g2_sk(
    const bf16* __restrict__ x, const bf16* __restrict__ W,
    float* __restrict__ part)
{
    const int lane = threadIdx.x & 63;
    const int gw   = blockIdx.x * 4 + (threadIdx.x >> 6);  // 0..5119
    const int tile = gw >> 2;
    const int s    = gw & 3;
    const int wm = tile / 10;       // 0..127
    const int wn = tile % 10;       // 0..9
    const int idx16 = lane & 15, quad = lane >> 4;
    const int k0 = s * 1024;

    floatx4 acc = {};
    const bf16* Ap = x + (size_t)(wm * 16 + idx16) * DINNER + quad * 8 + k0;
    const bf16* Bp = W + (size_t)(wn * 16 + idx16) * DINNER + quad * 8 + k0;
    for (int k = 0; k < 1024; k += 32) {
        short8 af  = *(const short8*)(Ap + k);
        short8 bfr = *(const short8*)(Bp + k);
        acc = __builtin_amdgcn_mfma_f32_16x16x32_bf16(af, bfr, acc, 0, 0, 0);
    }
    #pragma unroll
    for (int r = 0; r < 4; r++)
        part[((size_t)s * NROWS + wm * 16 + quad * 4 + r) * 160 + wn * 16 + idx16]
            = acc[r];
}

__global__ __launch_bounds__(256) void g2_reduce_kernel(
    const float* __restrict__ part, bf16* __restrict__ xdbl)
{
    int i = blockIdx.x * 256 + threadIdx.x;        // over 2048*160
    float v = part[i] + part[327680 + i] + part[2 * 327680 + i]
            + part[3 * 327680 + i];
    xdbl[i] = f2b(v);
}

// ---------------------------------------------------------------------------
// G3 direct (unchanged)
// ---------------------------------------------------------------------------
__global__ __launch_bounds__(256) void gemm_g3_direct(
    const bf16* __restrict__ xdbl, const bf16* __restrict__ W,
    const float* __restrict__ bias, bf16* __restrict__ dtout)
{
    const int lane = threadIdx.x & 63;
    const int gw   = blockIdx.x * 4 + (threadIdx.x >> 6);  // 0..32767
    const int wm = gw >> 8;         // 0..127
    const int wn = gw & 255;        // 0..255
    const int idx16 = lane & 15, quad = lane >> 4;

    floatx4 acc = {};
    const bf16* Ap = xdbl + (size_t)(wm * 16 + idx16) * 160 + quad * 8;
    const bf16* Bp = W + (size_t)(wn * 16 + idx16) * DTRANK + quad * 8;
    #pragma unroll
    for (int k = 0; k < 128; k += 32) {
        short8 af  = *(const short8*)(Ap + k);
        short8 bfr = *(const short8*)(Bp + k);
        acc = __builtin_amdgcn_mfma_f32_16x16x32_bf16(af, bfr, acc, 0, 0, 0);
    }
    const int c = wn * 16 + idx16;
    const float bv = bias[c];
    #pragma unroll
    for (int r = 0; r < 4; r++)
        dtout[(size_t)(wm * 16 + quad * 4 + r) * (2 * DINNER) + c]
            = f2b(softplus_safe(acc[r] + bv));
}

// ---------------------------------------------------------------------------
// K2: depthwise causal conv + bias + silu, 8 d-elems/thread (short8/float4)
// ---------------------------------------------------------------------------
__global__ __launch_bounds__(256) void conv_silu_kernel(
    const bf16* __restrict__ xz, const float* __restrict__ cw,
    const float* __restrict__ cb, bf16* __restrict__ xout)
{
    const int idx = (blockIdx.x * 256 + threadIdx.x) * 8;   // over NROWS*DINNER
    const int d0 = idx & (DINNER - 1);                      // multiple of 8
    const int bl = idx >> 12;
    const int l  = bl & (L_SZ - 1);
    const int b  = bl >> 10;

    float acc[8];
    {
        float4 c0 = *(const float4*)(cb + d0);
        float4 c1 = *(const float4*)(cb + d0 + 4);
        acc[0] = c0.x; acc[1] = c0.y; acc[2] = c0.z; acc[3] = c0.w;
        acc[4] = c1.x; acc[5] = c1.y; acc[6] = c1.z; acc[7] = c1.w;
    }
    floatx4 cwv[8];
    #pragma unroll
    for (int i = 0; i < 8; i++)
        cwv[i] = *(const floatx4*)(cw + (size_t)(d0 + i) * DCONV);

    #pragma unroll
    for (int t = 0; t < DCONV; t++) {
        int ls = l - (DCONV - 1) + t;
        if (ls >= 0) {
            short8 v = *(const short8*)(xz + ((size_t)(b * L_SZ + ls)) * (2 * DINNER) + d0);
            float xf[8]; cvt8(v, xf);
            #pragma unroll
            for (int i = 0; i < 8; i++) acc[i] += cwv[i][t] * xf[i];
        }
    }
    short8 o;
    #pragma unroll
    for (int i = 0; i < 8; i++) {
        float s = acc[i] / (1.f + __expf(-acc[i]));
        o[i] = f2bs(s);
    }
    *(short8*)(xout + idx) = o;
}

// ---------------------------------------------------------------------------
// Chunked selective scan — pair-split states (8/thread), LDS-staged f32 B/C,
// time-loop unrolled x4 with grouped loads.  (verified round 2)
// ---------------------------------------------------------------------------
__global__ __launch_bounds__(256) void scan_part1(
    const bf16* __restrict__ xz, const bf16* __restrict__ x,
    const bf16* __restrict__ xdbl, const float* __restrict__ A_log,
    float* __restrict__ hpart, float* __restrict__ dtsum)
{
    __shared__ float sBC[64 * 32];          // 8KB: chunk rows, cols B(16)|C(16)
    const int tid = threadIdx.x, bid = blockIdx.x;
    const int sub = tid & 1;
    const int d   = ((bid & 31) << 7) + (tid >> 1);
    const int b   = (bid >> 5) & 1;
    const int c   = bid >> 6;
    const size_t row0 = (size_t)b * L_SZ + c * CHUNKLEN;

    {   // stage B/C -> f32 LDS (2048 elems, 8/thread)
        int r = tid >> 2, sl = tid & 3;
        short8 v = *(const short8*)(xdbl + (row0 + r) * 160 + DTRANK + sl * 8);
        float tmp[8]; cvt8(v, tmp);
        #pragma unroll
        for (int i = 0; i < 8; i++) sBC[r * 32 + sl * 8 + i] = tmp[i];
    }
    __syncthreads();

    float Aa[8];
    #pragma unroll
    for (int s = 0; s < 8; s++)
        Aa[s] = -__expf(A_log[d * DSTATE + sub * 8 + s]);

    float h[8] = {};
    float dts = 0.f;
    const floatx4* BC4 = (const floatx4*)sBC;
    const int bc0 = sub * 2;

    #pragma unroll 1
    for (int l0 = 0; l0 < CHUNKLEN; l0 += 4) {
        float dtv[4], xv[4];
        #pragma unroll
        for (int u = 0; u < 4; u++) {
            const size_t rbl = row0 + l0 + u;
            dtv[u] = b2f(xz[rbl * (2 * DINNER) + d]);
            xv[u]  = b2f(x[rbl * DINNER + d]);
        }
        #pragma unroll
        for (int u = 0; u < 4; u++) {
            const int l = l0 + u;
            floatx4 B0 = BC4[l * 8 + bc0];
            floatx4 B1 = BC4[l * 8 + bc0 + 1];
            dts += dtv[u];
            float dx = dtv[u] * xv[u];
            #pragma unroll
            for (int s = 0; s < 4; s++)
                h[s] = __expf(dtv[u] * Aa[s]) * h[s] + dx * B0[s];
            #pragma unroll
            for (int s = 0; s < 4; s++)
                h[s + 4] = __expf(dtv[u] * Aa[s + 4]) * h[s + 4] + dx * B1[s];
        }
    }
    const size_t sbase = ((size_t)((b * DINNER + d) * NCHUNK + c)) * 16 + sub * 8;
    *(floatx4*)(hpart + sbase)     = (floatx4){h[0], h[1], h[2], h[3]};
    *(floatx4*)(hpart + sbase + 4) = (floatx4){h[4], h[5], h[6], h[7]};
    if (!sub) dtsum[(b * DINNER + d) * NCHUNK + c] = dts;
}

__global__ __launch_bounds__(256) void scan_part2(
    const float* __restrict__ A_log, float* hpart,
    const float* __restrict__ dtsum)
{
    const int t = blockIdx.x * 256 + threadIdx.x;
    const int s = t & 15;
    const int d = (t >> 4) & (DINNER - 1);
    const int b = t >> 16;
    const float Aa = -__expf(A_log[d * DSTATE + s]);
    const size_t base = (size_t)(b * DINNER + d) * NCHUNK;
    float h = 0.f;
    #pragma unroll
    for (int c = 0; c < NCHUNK; c++) {
        float tmp = hpart[(base + c) * 16 + s];
        hpart[(base + c) * 16 + s] = h;
        h = __expf(Aa * dtsum[base + c]) * h + tmp;
    }
}

__global__ __launch_bounds__(256) void scan_part3(
    const bf16* __restrict__ xz, const bf16* x,
    const bf16* __restrict__ xdbl, const float* __restrict__ A_log,
    const float* __restrict__ Dp, const float* __restrict__ hpart,
    bf16* y)
{
    __shared__ float sBC[64 * 32];
    const int tid = threadIdx.x, bid = blockIdx.x;
    const int sub = tid & 1;
    const int d   = ((bid & 31) << 7) + (tid >> 1);
    const int b   = (bid >> 5) & 1;
    const int c   = bid >> 6;
    const size_t row0 = (size_t)b * L_SZ + c * CHUNKLEN;

    {   // stage B/C -> f32 LDS
        int r = tid >> 2, sl = tid & 3;
        short8 v = *(const short8*)(xdbl + (row0 + r) * 160 + DTRANK + sl * 8);
        float tmp[8]; cvt8(v, tmp);
        #pragma unroll
        for (int i = 0; i < 8; i++) sBC[r * 32 + sl * 8 + i] = tmp[i];
    }
    __syncthreads();

    float Aa[8];
    #pragma unroll
    for (int s = 0; s < 8; s++)
        Aa[s] = -__expf(A_log[d * DSTATE + sub * 8 + s]);
    const float Dv = Dp[d];

    float h[8];
    const size_t sbase = ((size_t)((b * DINNER + d) * NCHUNK + c)) * 16 + sub * 8;
    {
        floatx4 h0 = *(const floatx4*)(hpart + sbase);
        floatx4 h1 = *(const floatx4*)(hpart + sbase + 4);
        #pragma unroll
        for (int s = 0; s < 4; s++) { h[s] = h0[s]; h[s + 4] = h1[s]; }
    }

    const floatx4* BC4 = (const floatx4*)sBC;
    const int bc0 = sub * 2;

    #pragma unroll 1
    for (int l0 = 0; l0 < CHUNKLEN; l0 += 4) {
        float dtv[4], xv[4], zv[4];
        #pragma unroll
        for (int u = 0; u < 4; u++) {
            const size_t rbl = row0 + l0 + u;
            dtv[u] = b2f(xz[rbl * (2 * DINNER) + d]);
            xv[u]  = b2f(x[rbl * DINNER + d]);
            zv[u]  = b2f(xz[rbl * (2 * DINNER) + DINNER + d]);
        }
        #pragma unroll
        for (int u = 0; u < 4; u++) {
            const int l = l0 + u;
            floatx4 B0 = BC4[l * 8 + bc0];
            floatx4 B1 = BC4[l * 8 + bc0 + 1];
            floatx4 C0 = BC4[l * 8 + 4 + bc0];
            floatx4 C1 = BC4[l * 8 + 4 + bc0 + 1];
            float dx = dtv[u] * xv[u];
            float ys = 0.f;
            #pragma unroll
            for (int s = 0; s < 4; s++) {
                h[s] = __expf(dtv[u] * Aa[s]) * h[s] + dx * B0[s];
                ys += h[s] * C0[s];
            }
            #pragma unroll
            for (int s = 0; s < 4; s++) {
                h[s + 4] = __expf(dtv[u] * Aa[s + 4]) * h[s + 4] + dx * B1[s];
                ys += h[s + 4] * C1[s];
            }
            ys += __shfl_xor(ys, 1);
            if (!sub) {
                const size_t rbl = row0 + l;
                float sig = zv[u] / (1.f + __expf(-zv[u]));
                y[rbl * DINNER + d] = f2b((ys + xv[u] * Dv) * sig);
            }
        }
    }
}

// ---------------------------------------------------------------------------
extern "C" void kernel_launch(void* const* d_in, const int* in_sizes, int n_in,
                              void* d_out, int out_size, void* d_ws, size_t ws_size,
                              hipStream_t stream)
{
    // ws (proven >= 50,987,012 B):
    //   [0, 32MB)        xz bf16 [2048][8192]; dead after scan_p3 -> G4's C1 (fp32 16.8MB)
    //   [32MB, 48MB)     hs bf16 (8.4MB, dead after G1) -> x bf16 [2048][4096] -> y alias
    //   [48MB, +640KB)   xdbl bf16 [2048][160]
    //   +4B              dtype flag
    // d_out (33.5MB) phase-by-phase: see round-0 comment (unchanged).
    const size_t WS_NEED = 33554432ull + 16777216ull + 655360ull + 4ull;
    if (ws_size < WS_NEED) {
        fill_diag_kernel<<<(out_size + 255) / 256, 256, 0, stream>>>(
            (unsigned short*)d_out, out_size);
        return;
    }

    char* ws = (char*)d_ws;
    bf16*  xz    = (bf16*)(ws);
    float* c1    = (float*)(ws);                 // G4 partial (xz dead)
    bf16*  hs    = (bf16*)(ws + 33554432);
    bf16*  x     = (bf16*)(ws + 33554432);       // overwrites dead hs
    bf16*  y     = x;
    bf16*  xdbl  = (bf16*)(ws + 50331648);
    int*   flag  = (int*)(ws + 50987008);

    char* od = (char*)d_out;
    bf16*  w1bf  = (bf16*)od;                     // phase A
    bf16*  wdtbf = (bf16*)od;                     // phase B
    bf16*  wxbf  = (bf16*)(od + 1048576);
    float* dtsum = (float*)(od + 2359296);
    float* hpart = (float*)(od + 2883584);
    float* g2part= (float*)(od + 11272192);       // 5.24MB, ends 16.52MB
    bf16*  wobf  = (bf16*)(od + 16777216);
    float* outp  = (float*)d_out;
    float* resp  = (float*)d_out + (size_t)NROWS * DMODEL;

    const float* hid = (const float*)d_in[0];
    const float* res = (const float*)d_in[1];
    const float* nw  = (const float*)d_in[2];
    const float* w1  = (const float*)d_in[3];
    const float* cw  = (const float*)d_in[4];
    const float* cb  = (const float*)d_in[5];
    const float* wx  = (const float*)d_in[6];
    const float* wdt = (const float*)d_in[7];
    const float* bdt = (const float*)d_in[8];
    const float* Al  = (const float*)d_in[9];
    const float* Dp  = (const float*)d_in[10];
    const float* wo  = (const float*)d_in[11];

    probe_kernel<<<1, 64, 0, stream>>>(d_in[2], flag);

    // Phase A: hs + full w1bf, then single-launch G1 (256 blocks = 1 blk/CU)
    addnorm_kernel<<<NROWS, 256, 0, stream>>>(hid, res, nw, hs);
    cvt_w_kernel<<<(2 * DINNER * DMODEL) / 2048, 256, 0, stream>>>(
        w1, w1bf, 2 * DINNER * DMODEL);
    gemm_bigtile<<<(2048 / 256) * (8192 / 256), 512, 0, stream>>>(
        hs, w1bf, xz, 2 * DINNER, DMODEL, DMODEL, DMODEL, 2 * DINNER);

    // Phase B: d_out is dead scratch
    cvt_w_kernel<<<(DINNER * DTRANK) / 2048, 256, 0, stream>>>(
        wdt, wdtbf, DINNER * DTRANK);
    cvt_w_kernel<<<(160 * DINNER) / 2048, 256, 0, stream>>>(
        wx, wxbf, 160 * DINNER);
    cvt_w_kernel<<<(DMODEL * DINNER) / 2048, 256, 0, stream>>>(
        wo, wobf, DMODEL * DINNER);

    conv_silu_kernel<<<(NROWS * DINNER) / 2048, 256, 0, stream>>>(xz, cw, cb, x);

    // G2: split-K=4 direct MFMA -> fp32 partials -> bf16 xdbl
    gemm_g2_sk<<<1280, 256, 0, stream>>>(x, wxbf, g2part);
    g2_reduce_kernel<<<(NROWS * 160) / 256, 256, 0, stream>>>(g2part, xdbl);

    // G3: direct K=128 GEMM + softplus -> dt into xz x-half
    gemm_g3_direct<<<8192, 256, 0, stream>>>(xdbl, wdtbf, bdt, xz);

    // chunked scan (pair-split: 2 threads per (b,d,c))
    scan_part1<<<(NCHUNK * B_SZ * DINNER * 2) / 256, 256, 0, stream>>>(
        xz, x, xdbl, Al, hpart, dtsum);
    scan_part2<<<(B_SZ * DINNER * DSTATE) / 256, 256, 0, stream>>>(
        Al, hpart, dtsum);
    scan_part3<<<(NCHUNK * B_SZ * DINNER * 2) / 256, 256, 0, stream>>>(
        xz, x, xdbl, Al, Dp, hpart, y);

    // Phase C: G4 split-K=2 ring-4 (C0 = outp, C1 = dead xz region), then sum
    gemm_sk2_r4<<<512, 256, 0, stream>>>(y, wobf, outp, c1);
    addf_kernel<<<(NROWS * DMODEL) / 1024, 256, 0, stream>>>(outp, c1);

    // Phase D: residual output (wobf region now dead)
    residual_out_kernel<<<(NROWS * DMODEL) / 1024, 256, 0, stream>>>(
        hid, res, resp);

    assert_fp32_kernel<<<16, 256, 0, stream>>>(flag, outp);
}